// Round 1
// baseline (10240.893 us; speedup 1.0000x reference)
//
#include <hip/hip_runtime.h>
#include <hip/hip_bf16.h>

// SNN: B=256, IN=1024, HID=2048, OUT=10, T=100, decay=0.9, thr=1.0, reset=0.
// Layer-pipelined: GEMM1(all t) -> LIF scan -> GEMM2(all t) -> scan -> GEMM3 -> scan.
// fp64 accumulation everywhere to match a (presumed) float64 numpy reference:
// the LIF threshold makes the system chaotic, so we want to be as close to the
// true sum as possible. Spikes are bit-packed; GEMMs are "sum of selected
// weight rows" done as fma(bit, w, acc) with wave-uniform scalar weights.

#define B 256
#define IN_DIM 1024
#define HID 2048
#define OUT_DIM 10
#define T_STEPS 100

typedef unsigned long long ull;

// ---------------- weight fp32 -> fp64 conversion ----------------
__global__ __launch_bounds__(256) void cvt_weights(
    const float* __restrict__ wih, const float* __restrict__ whh,
    const float* __restrict__ who,
    double* __restrict__ Wih, double* __restrict__ Whh, double* __restrict__ Who)
{
    int i = blockIdx.x * 256 + threadIdx.x;
    if (i < IN_DIM * HID) Wih[i] = (double)wih[i];
    if (i < HID * HID)    Whh[i] = (double)whh[i];
    if (i < HID * OUT_DIM) Who[i] = (double)who[i];
}

// ---------------- bit-pack input spikes ----------------
// input_bins layout [B, IN_DIM, T]; produce Xbits[(t*256+b)*16 + i/64] bit i&63.
__global__ __launch_bounds__(256) void bitpack_input(
    const float* __restrict__ inp, ull* __restrict__ Xbits)
{
    int g = blockIdx.x * 4 + (threadIdx.x >> 6);   // 0..4095 waves
    int lane = threadIdx.x & 63;
    int b = g >> 4;          // 0..255
    int ig = g & 15;         // 0..15 (i-group of 64)
    int i = ig * 64 + lane;
    const float* p = inp + ((size_t)b * IN_DIM + i) * T_STEPS;
    for (int t = 0; t < T_STEPS; ++t) {
        ull m = __ballot(p[t] > 0.5f);
        if (lane == 0) Xbits[((size_t)t * B + b) * 16 + ig] = m;
    }
}

// ---------------- bit-GEMM: C[row, n] = sum_k bit(row,k) * W[k, n] ----------
// rows = local chunk rows (t_local*256+b); bits indexed at row+bits_row_off.
// wave = 64 rows x 32 cols of fp64 acc; weight loads wave-uniform (scalar).
__global__ __launch_bounds__(256) void gemm_bits(
    const ull* __restrict__ bits, int wpr, int bits_row_off,
    const double* __restrict__ W, double* __restrict__ C)
{
    const int lane = threadIdx.x & 63;
    const int wave = threadIdx.x >> 6;
    const int row = blockIdx.x * 64 + lane;
    int n0 = blockIdx.y * 128 + wave * 32;
    n0 = __builtin_amdgcn_readfirstlane(n0);
    const double* __restrict__ wb = W + n0;

    double acc[32];
#pragma unroll
    for (int j = 0; j < 32; ++j) acc[j] = 0.0;

    const ull* __restrict__ brow = bits + (size_t)(row + bits_row_off) * wpr;
    for (int w = 0; w < wpr; ++w) {
        ull m = brow[w];
        const double* __restrict__ wk = wb + (size_t)(w * 64) * HID;
#pragma unroll 4
        for (int kk = 0; kk < 64; ++kk) {
            double bd = (double)(unsigned int)(m & 1ull);
            m >>= 1;
#pragma unroll
            for (int j = 0; j < 32; ++j)
                acc[j] = fma(bd, wk[j], acc[j]);
            wk += HID;
        }
    }
    double* __restrict__ crow = C + (size_t)row * HID + n0;
#pragma unroll
    for (int j = 0; j < 32; ++j) crow[j] = acc[j];
}

// ---------------- output bit-GEMM: 10 columns ----------------
__global__ __launch_bounds__(256) void gemm_out(
    const ull* __restrict__ bits, int bits_row_off,
    const double* __restrict__ W, double* __restrict__ C3)
{
    const int lane = threadIdx.x & 63;
    const int wave = threadIdx.x >> 6;
    const int row = blockIdx.x * 256 + wave * 64 + lane;

    double acc[OUT_DIM];
#pragma unroll
    for (int j = 0; j < OUT_DIM; ++j) acc[j] = 0.0;

    const ull* __restrict__ brow = bits + (size_t)(row + bits_row_off) * 32;
    for (int w = 0; w < 32; ++w) {
        ull m = brow[w];
        const double* __restrict__ wk = W + (size_t)(w * 64) * OUT_DIM;
#pragma unroll 4
        for (int kk = 0; kk < 64; ++kk) {
            double bd = (double)(unsigned int)(m & 1ull);
            m >>= 1;
#pragma unroll
            for (int j = 0; j < OUT_DIM; ++j)
                acc[j] = fma(bd, wk[j], acc[j]);
            wk += OUT_DIM;
        }
    }
    double* __restrict__ crow = C3 + (size_t)row * OUT_DIM;
#pragma unroll
    for (int j = 0; j < OUT_DIM; ++j) crow[j] = acc[j];
}

// ---------------- LIF scan for a hidden layer (2048 units) ----------------
// wave per (b, n-group-of-64); sequential over Tl local steps; ballot -> bits.
__global__ __launch_bounds__(256) void lif_scan(
    const double* __restrict__ C, double* __restrict__ vstate,
    ull* __restrict__ Sbits, int bits_row_off, int Tl, int first)
{
    int g = blockIdx.x * 4 + (threadIdx.x >> 6);  // 0..8191
    int lane = threadIdx.x & 63;
    int b = g >> 5;        // 0..255
    int ng = g & 31;       // 0..31
    int n = ng * 64 + lane;
    double v = first ? 0.0 : vstate[(size_t)b * HID + n];
    for (int tl = 0; tl < Tl; ++tl) {
        double c = C[((size_t)tl * B + b) * HID + n];
        v = v * 0.9 + c;
        bool s = (v >= 1.0);
        if (s) v = 0.0;
        ull mask = __ballot(s);
        if (lane == 0)
            Sbits[((size_t)(bits_row_off + tl * B + b)) * 32 + ng] = mask;
    }
    vstate[(size_t)b * HID + n] = v;
}

// ---------------- output LIF scan + rate accumulation ----------------
__global__ __launch_bounds__(256) void lif_out(
    const double* __restrict__ C3, double* __restrict__ vstate,
    int* __restrict__ cnt_state, float* __restrict__ out, int Tl, int first)
{
    int tid = blockIdx.x * 256 + threadIdx.x;
    if (tid >= B * OUT_DIM) return;
    int b = tid / OUT_DIM, o = tid % OUT_DIM;
    double v = first ? 0.0 : vstate[tid];
    int cnt = first ? 0 : cnt_state[tid];
    for (int tl = 0; tl < Tl; ++tl) {
        double c = C3[((size_t)tl * B + b) * OUT_DIM + o];
        v = v * 0.9 + c;
        if (v >= 1.0) { cnt++; v = 0.0; }
    }
    vstate[tid] = v;
    cnt_state[tid] = cnt;
    out[tid] = (float)((double)cnt / (double)T_STEPS);
}

extern "C" void kernel_launch(void* const* d_in, const int* in_sizes, int n_in,
                              void* d_out, int out_size, void* d_ws, size_t ws_size,
                              hipStream_t stream) {
    const float* inp = (const float*)d_in[0];   // [256,1024,100]
    const float* wih = (const float*)d_in[1];   // [1024,2048]
    const float* whh = (const float*)d_in[2];   // [1,2048,2048]
    const float* who = (const float*)d_in[3];   // [2048,10]
    float* out = (float*)d_out;                 // [256,10]

    // ---- workspace layout ----
    unsigned char* p = (unsigned char*)d_ws;
    auto alloc = [&](size_t sz) -> void* {
        void* r = (void*)p;
        p += (sz + 255) & ~(size_t)255;
        return r;
    };
    double* Wih64 = (double*)alloc((size_t)IN_DIM * HID * 8);      // 16.8 MB
    double* Whh64 = (double*)alloc((size_t)HID * HID * 8);         // 33.6 MB
    double* Who64 = (double*)alloc((size_t)HID * OUT_DIM * 8);
    ull* Xbits = (ull*)alloc((size_t)T_STEPS * B * 16 * 8);        // 3.3 MB
    ull* S1    = (ull*)alloc((size_t)T_STEPS * B * 32 * 8);        // 6.6 MB
    ull* S2    = (ull*)alloc((size_t)T_STEPS * B * 32 * 8);        // 6.6 MB
    double* v1 = (double*)alloc((size_t)B * HID * 8);
    double* v2 = (double*)alloc((size_t)B * HID * 8);
    double* vo = (double*)alloc((size_t)B * OUT_DIM * 8);
    int* cnts  = (int*)alloc((size_t)B * OUT_DIM * 4);

    size_t used = (size_t)(p - (unsigned char*)d_ws);
    size_t remain = (ws_size > used) ? (ws_size - used) : 0;
    size_t per_t = (size_t)B * HID * 8 + (size_t)B * OUT_DIM * 8 + 1024;
    int CH = (int)(remain / per_t);
    if (CH > T_STEPS) CH = T_STEPS;
    if (CH < 1) CH = 1;  // if ws is too small nothing works anyway
    double* C3 = (double*)alloc((size_t)CH * B * OUT_DIM * 8);
    double* C  = (double*)alloc((size_t)CH * B * HID * 8);

    // ---- one-time prep (runs every call; cheap) ----
    cvt_weights<<<(HID * HID + 255) / 256, 256, 0, stream>>>(
        wih, whh, who, Wih64, Whh64, Who64);
    bitpack_input<<<(B * (IN_DIM / 64)) / 4, 256, 0, stream>>>(inp, Xbits);

    // ---- chunked time loop ----
    for (int t0 = 0; t0 < T_STEPS; t0 += CH) {
        int L = T_STEPS - t0;
        if (L > CH) L = CH;
        int rows = L * B;            // multiple of 64
        int first = (t0 == 0) ? 1 : 0;

        // layer 1: currents for all local t
        gemm_bits<<<dim3(rows / 64, HID / 128), 256, 0, stream>>>(
            Xbits, 16, t0 * B, Wih64, C);
        lif_scan<<<(B * (HID / 64)) / 4, 256, 0, stream>>>(
            C, v1, S1, t0 * B, L, first);

        // layer 2
        gemm_bits<<<dim3(rows / 64, HID / 128), 256, 0, stream>>>(
            S1, 32, t0 * B, Whh64, C);
        lif_scan<<<(B * (HID / 64)) / 4, 256, 0, stream>>>(
            C, v2, S2, t0 * B, L, first);

        // output layer
        gemm_out<<<rows / 256, 256, 0, stream>>>(S2, t0 * B, Who64, C3);
        lif_out<<<(B * OUT_DIM + 255) / 256, 256, 0, stream>>>(
            C3, vo, cnts, out, L, first);
    }
}